// Round 6
// baseline (910.969 us; speedup 1.0000x reference)
//
#include <hip/hip_runtime.h>
#include <hip/hip_bf16.h>

// GCN forward, CSR-gather, fused gather+GEMM (R4 structure) + CROSS-TASK
// PREFETCH. Each wave owns 2 consecutive 8-node tasks; after gathering task A
// (pair-zipped, 16 rows in flight) it issues task B's 8 initial self-loop row
// loads BEFORE running task A's GEMM -> those loads fly during the GEMM phase,
// covering the memory-pipe bubble (R4: BW = 3.89 TB/s during gather, 0 during
// GEMM -> avg 2.84). 6250 waves = single resident generation (no regen gap).
// MLP head: 4 graphs/block to amortize W streaming. cnt zeroed via memset.

#define NN 100000
#define NE 1600000
#define NG 512
#define NBLK ((NN + 1023) / 1024)   // 98 scan blocks

typedef float v2f __attribute__((ext_vector_type(2)));

// ---------------- CSR build (counting sort by dst) ----------------

__global__ void k_hist(const int* __restrict__ dst, int* cnt, int e) {
    int i = blockIdx.x * blockDim.x + threadIdx.x;
    if (i < e) atomicAdd(&cnt[dst[i]], 1);
}

// fused: dinv[i] = rsqrt(cnt[i]+1)  and  gmax zero-init (NG*256 = 131072)
__global__ void k_prep(const int* __restrict__ cnt, float* __restrict__ dinv,
                       float* __restrict__ gmax) {
    int i = blockIdx.x * blockDim.x + threadIdx.x;
    if (i < NN) dinv[i] = rsqrtf((float)cnt[i] + 1.0f);
    if (i < NG * 256) gmax[i] = 0.0f;
}

__global__ __launch_bounds__(256) void k_bsum(const int* __restrict__ cnt, int* __restrict__ bsum) {
    __shared__ int s[256];
    int b = blockIdx.x, t = threadIdx.x;
    int base = b * 1024 + t * 4;
    int v = 0;
#pragma unroll
    for (int j = 0; j < 4; j++) { int i = base + j; if (i < NN) v += cnt[i]; }
    s[t] = v; __syncthreads();
    for (int off = 128; off > 0; off >>= 1) {
        if (t < off) s[t] += s[t + off];
        __syncthreads();
    }
    if (t == 0) bsum[b] = s[0];
}

__global__ __launch_bounds__(128) void k_scan_bsum(int* bsum, int* row_ptr) {
    __shared__ int s[128];
    int t = threadIdx.x;
    int v = (t < NBLK) ? bsum[t] : 0;
    s[t] = v; __syncthreads();
    for (int off = 1; off < 128; off <<= 1) {
        int u = (t >= off) ? s[t - off] : 0;
        __syncthreads();
        s[t] += u;
        __syncthreads();
    }
    if (t < NBLK) bsum[t] = s[t] - v;
    if (t == 0) row_ptr[NN] = NE;
}

__global__ __launch_bounds__(256) void k_scan_blocks(const int* __restrict__ cnt,
    const int* __restrict__ bsum, int* __restrict__ row_ptr, int* __restrict__ cursor) {
    __shared__ int s[256];
    int b = blockIdx.x, t = threadIdx.x;
    int base = b * 1024 + t * 4;
    int v[4]; int sum = 0;
#pragma unroll
    for (int j = 0; j < 4; j++) { int i = base + j; v[j] = (i < NN) ? cnt[i] : 0; sum += v[j]; }
    s[t] = sum; __syncthreads();
    for (int off = 1; off < 256; off <<= 1) {
        int u = (t >= off) ? s[t - off] : 0;
        __syncthreads();
        s[t] += u;
        __syncthreads();
    }
    int excl = s[t] - sum + bsum[b];
#pragma unroll
    for (int j = 0; j < 4; j++) {
        int i = base + j;
        if (i < NN) { row_ptr[i] = excl; cursor[i] = excl; excl += v[j]; }
    }
}

// counting-sort fill: one packed 8B store per edge: es[pos] = {src, w}
__global__ void k_fillslots(const int* __restrict__ src, const int* __restrict__ dst,
    const float* __restrict__ dinv, int* cursor, int2* __restrict__ es, int e) {
    int i = blockIdx.x * blockDim.x + threadIdx.x;
    if (i >= e) return;
    int s = src[i], d = dst[i];
    int pos = atomicAdd(&cursor[d], 1);
    es[pos] = make_int2(s, __float_as_int(dinv[s] * dinv[d]));
}

// ---------------- fused1: pair-zip gather78 + gemm1, 2 tasks/wave + prefetch ----------------
__global__ __launch_bounds__(256) void k_fused1(const float* __restrict__ x,
    const int* __restrict__ rp, const int2* __restrict__ es,
    const float* __restrict__ dinv, const float* __restrict__ W,
    const float* __restrict__ bias, float* __restrict__ out) {
    __shared__ float As[4][8][80];   // 10 KB
    int tid = threadIdx.x;
    int wv = tid >> 6, l = tid & 63;
    int w = __builtin_amdgcn_readfirstlane(blockIdx.x * 4 + wv);  // 6250 workers
    if (w >= 6250) return;
    int n0 = w * 16;

    int f0 = l * 2;
    float2 bv = *(const float2*)&bias[f0];

    float2 init[8];
    if (l < 39) {
#pragma unroll
        for (int i = 0; i < 8; i++)
            init[i] = ((const float2*)(x + (size_t)(n0 + i) * 78))[l];
    }

    for (int it = 0; it < 2; it++) {
        int b0 = n0 + it * 8;
        if (l < 39) {
            for (int pi = 0; pi < 4; pi++) {
                int nA = b0 + 2 * pi, nB = nA + 1;
                float diA = dinv[nA], swA = diA * diA;
                float diB = dinv[nB], swB = diB * diB;
                float2 aA = init[2 * pi], aB = init[2 * pi + 1];
                aA.x *= swA; aA.y *= swA;
                aB.x *= swB; aB.y *= swB;
                int eA = rp[nA], eA1 = rp[nA + 1];
                int eB = rp[nB], eB1 = rp[nB + 1];
                int cA = (eA1 - eA) >> 3, cB = (eB1 - eB) >> 3;
                while (cA > 0 || cB > 0) {
                    bool dA = (cA > 0), dB = (cB > 0);
                    int2 esA[8], esB[8];
                    float2 vA[8], vB[8];
                    if (dA) {
#pragma unroll
                        for (int j = 0; j < 8; j++) esA[j] = es[eA + j];
                    }
                    if (dB) {
#pragma unroll
                        for (int j = 0; j < 8; j++) esB[j] = es[eB + j];
                    }
                    if (dA) {
#pragma unroll
                        for (int j = 0; j < 8; j++)
                            vA[j] = ((const float2*)(x + (size_t)esA[j].x * 78))[l];
                    }
                    if (dB) {
#pragma unroll
                        for (int j = 0; j < 8; j++)
                            vB[j] = ((const float2*)(x + (size_t)esB[j].x * 78))[l];
                    }
                    if (dA) {
#pragma unroll
                        for (int j = 0; j < 8; j++) {
                            float ww = __int_as_float(esA[j].y);
                            aA.x += vA[j].x * ww; aA.y += vA[j].y * ww;
                        }
                        eA += 8; cA--;
                    }
                    if (dB) {
#pragma unroll
                        for (int j = 0; j < 8; j++) {
                            float ww = __int_as_float(esB[j].y);
                            aB.x += vB[j].x * ww; aB.y += vB[j].y * ww;
                        }
                        eB += 8; cB--;
                    }
                }
                while (eA < eA1 && eB < eB1) {
                    int2 pA = es[eA], pB = es[eB];
                    float2 vA2 = ((const float2*)(x + (size_t)pA.x * 78))[l];
                    float2 vB2 = ((const float2*)(x + (size_t)pB.x * 78))[l];
                    float wA = __int_as_float(pA.y), wB = __int_as_float(pB.y);
                    aA.x += vA2.x * wA; aA.y += vA2.y * wA;
                    aB.x += vB2.x * wB; aB.y += vB2.y * wB;
                    eA++; eB++;
                }
                for (; eA < eA1; eA++) {
                    int2 p = es[eA];
                    float ww = __int_as_float(p.y);
                    float2 v = ((const float2*)(x + (size_t)p.x * 78))[l];
                    aA.x += v.x * ww; aA.y += v.y * ww;
                }
                for (; eB < eB1; eB++) {
                    int2 p = es[eB];
                    float ww = __int_as_float(p.y);
                    float2 v = ((const float2*)(x + (size_t)p.x * 78))[l];
                    aB.x += v.x * ww; aB.y += v.y * ww;
                }
                *(float2*)&As[wv][2 * pi][2 * l] = aA;
                *(float2*)&As[wv][2 * pi + 1][2 * l] = aB;
            }
            // cross-task prefetch: next task's initial rows fly during GEMM
            if (it == 0) {
#pragma unroll
                for (int i = 0; i < 8; i++)
                    init[i] = ((const float2*)(x + (size_t)(b0 + 8 + i) * 78))[l];
            }
        }
        // same-wave producer/consumer: lgkmcnt ordering, no barrier.

        float2 acc[8];
#pragma unroll
        for (int i = 0; i < 8; i++) acc[i] = make_float2(0.f, 0.f);

        for (int k = 0; k < 76; k += 4) {
            float2 w0 = *(const float2*)&W[(k + 0) * 128 + f0];
            float2 w1 = *(const float2*)&W[(k + 1) * 128 + f0];
            float2 w2 = *(const float2*)&W[(k + 2) * 128 + f0];
            float2 w3 = *(const float2*)&W[(k + 3) * 128 + f0];
#pragma unroll
            for (int i = 0; i < 8; i++) {
                float4 a = *(const float4*)&As[wv][i][k];
                acc[i].x += a.x * w0.x + a.y * w1.x + a.z * w2.x + a.w * w3.x;
                acc[i].y += a.x * w0.y + a.y * w1.y + a.z * w2.y + a.w * w3.y;
            }
        }
        {   // rows 76,77
            float2 w0 = *(const float2*)&W[76 * 128 + f0];
            float2 w1 = *(const float2*)&W[77 * 128 + f0];
#pragma unroll
            for (int i = 0; i < 8; i++) {
                float2 a = *(const float2*)&As[wv][i][76];
                acc[i].x += a.x * w0.x + a.y * w1.x;
                acc[i].y += a.x * w0.y + a.y * w1.y;
            }
        }
#pragma unroll
        for (int i = 0; i < 8; i++) {
            float2 o;
            o.x = fmaxf(acc[i].x + bv.x, 0.f);
            o.y = fmaxf(acc[i].y + bv.y, 0.f);
            *(float2*)&out[(size_t)(b0 + i) * 128 + f0] = o;
        }
    }
}

// ---------------- fused2: pair-zip gather128 + gemm2(pk_fma) + pool, 2 tasks/wave ----------------
__global__ __launch_bounds__(256) void k_fused2(const float* __restrict__ h,
    const int* __restrict__ rp, const int2* __restrict__ es,
    const float* __restrict__ dinv, const float* __restrict__ W,
    const float* __restrict__ bias, const int* __restrict__ batch,
    unsigned* __restrict__ gmax) {
    __shared__ float As[4][8][128];  // 16 KB
    int tid = threadIdx.x;
    int wv = tid >> 6, l = tid & 63;
    int w = __builtin_amdgcn_readfirstlane(blockIdx.x * 4 + wv);  // 6250 workers
    if (w >= 6250) return;
    int n0 = w * 16;

    int f0 = l * 4;
    float4 bv = *(const float4*)&bias[f0];

    float2 init[8];
#pragma unroll
    for (int i = 0; i < 8; i++)
        init[i] = ((const float2*)(h + (size_t)(n0 + i) * 128))[l];

    for (int it = 0; it < 2; it++) {
        int b0 = n0 + it * 8;
        for (int pi = 0; pi < 4; pi++) {
            int nA = b0 + 2 * pi, nB = nA + 1;
            float diA = dinv[nA], swA = diA * diA;
            float diB = dinv[nB], swB = diB * diB;
            float2 aA = init[2 * pi], aB = init[2 * pi + 1];
            aA.x *= swA; aA.y *= swA;
            aB.x *= swB; aB.y *= swB;
            int eA = rp[nA], eA1 = rp[nA + 1];
            int eB = rp[nB], eB1 = rp[nB + 1];
            int cA = (eA1 - eA) >> 3, cB = (eB1 - eB) >> 3;
            while (cA > 0 || cB > 0) {
                bool dA = (cA > 0), dB = (cB > 0);
                int2 esA[8], esB[8];
                float2 vA[8], vB[8];
                if (dA) {
#pragma unroll
                    for (int j = 0; j < 8; j++) esA[j] = es[eA + j];
                }
                if (dB) {
#pragma unroll
                    for (int j = 0; j < 8; j++) esB[j] = es[eB + j];
                }
                if (dA) {
#pragma unroll
                    for (int j = 0; j < 8; j++)
                        vA[j] = ((const float2*)(h + (size_t)esA[j].x * 128))[l];
                }
                if (dB) {
#pragma unroll
                    for (int j = 0; j < 8; j++)
                        vB[j] = ((const float2*)(h + (size_t)esB[j].x * 128))[l];
                }
                if (dA) {
#pragma unroll
                    for (int j = 0; j < 8; j++) {
                        float ww = __int_as_float(esA[j].y);
                        aA.x += vA[j].x * ww; aA.y += vA[j].y * ww;
                    }
                    eA += 8; cA--;
                }
                if (dB) {
#pragma unroll
                    for (int j = 0; j < 8; j++) {
                        float ww = __int_as_float(esB[j].y);
                        aB.x += vB[j].x * ww; aB.y += vB[j].y * ww;
                    }
                    eB += 8; cB--;
                }
            }
            while (eA < eA1 && eB < eB1) {
                int2 pA = es[eA], pB = es[eB];
                float2 vA2 = ((const float2*)(h + (size_t)pA.x * 128))[l];
                float2 vB2 = ((const float2*)(h + (size_t)pB.x * 128))[l];
                float wA = __int_as_float(pA.y), wB = __int_as_float(pB.y);
                aA.x += vA2.x * wA; aA.y += vA2.y * wA;
                aB.x += vB2.x * wB; aB.y += vB2.y * wB;
                eA++; eB++;
            }
            for (; eA < eA1; eA++) {
                int2 p = es[eA];
                float ww = __int_as_float(p.y);
                float2 v = ((const float2*)(h + (size_t)p.x * 128))[l];
                aA.x += v.x * ww; aA.y += v.y * ww;
            }
            for (; eB < eB1; eB++) {
                int2 p = es[eB];
                float ww = __int_as_float(p.y);
                float2 v = ((const float2*)(h + (size_t)p.x * 128))[l];
                aB.x += v.x * ww; aB.y += v.y * ww;
            }
            *(float2*)&As[wv][2 * pi][2 * l] = aA;
            *(float2*)&As[wv][2 * pi + 1][2 * l] = aB;
        }
        // cross-task prefetch: next task's initial rows fly during GEMM
        if (it == 0) {
#pragma unroll
            for (int i = 0; i < 8; i++)
                init[i] = ((const float2*)(h + (size_t)(b0 + 8 + i) * 128))[l];
        }
        // same-wave producer/consumer: no barrier needed.

        v2f acc[8][2];
#pragma unroll
        for (int i = 0; i < 8; i++) { acc[i][0] = (v2f)(0.f); acc[i][1] = (v2f)(0.f); }

        for (int k = 0; k < 128; k += 4) {
            float4 w0 = *(const float4*)&W[(size_t)(k + 0) * 256 + f0];
            float4 w1 = *(const float4*)&W[(size_t)(k + 1) * 256 + f0];
            float4 w2 = *(const float4*)&W[(size_t)(k + 2) * 256 + f0];
            float4 w3 = *(const float4*)&W[(size_t)(k + 3) * 256 + f0];
            v2f w0a = {w0.x, w0.y}, w0b = {w0.z, w0.w};
            v2f w1a = {w1.x, w1.y}, w1b = {w1.z, w1.w};
            v2f w2a = {w2.x, w2.y}, w2b = {w2.z, w2.w};
            v2f w3a = {w3.x, w3.y}, w3b = {w3.z, w3.w};
#pragma unroll
            for (int i = 0; i < 8; i++) {
                float4 a = *(const float4*)&As[wv][i][k];
                v2f sx = {a.x, a.x}, sy = {a.y, a.y}, sz = {a.z, a.z}, sw = {a.w, a.w};
                acc[i][0] = __builtin_elementwise_fma(sx, w0a, acc[i][0]);
                acc[i][1] = __builtin_elementwise_fma(sx, w0b, acc[i][1]);
                acc[i][0] = __builtin_elementwise_fma(sy, w1a, acc[i][0]);
                acc[i][1] = __builtin_elementwise_fma(sy, w1b, acc[i][1]);
                acc[i][0] = __builtin_elementwise_fma(sz, w2a, acc[i][0]);
                acc[i][1] = __builtin_elementwise_fma(sz, w2b, acc[i][1]);
                acc[i][0] = __builtin_elementwise_fma(sw, w3a, acc[i][0]);
                acc[i][1] = __builtin_elementwise_fma(sw, w3b, acc[i][1]);
            }
        }

        int curg = -1;
        float4 m = make_float4(0.f, 0.f, 0.f, 0.f);
#pragma unroll
        for (int i = 0; i < 8; i++) {
            int g = batch[b0 + i];
            float4 v;
            v.x = fmaxf(acc[i][0].x + bv.x, 0.f); v.y = fmaxf(acc[i][0].y + bv.y, 0.f);
            v.z = fmaxf(acc[i][1].x + bv.z, 0.f); v.w = fmaxf(acc[i][1].y + bv.w, 0.f);
            if (g != curg) {
                if (curg >= 0) {
                    unsigned* gp = &gmax[(size_t)curg * 256 + f0];
                    atomicMax(&gp[0], __float_as_uint(m.x));
                    atomicMax(&gp[1], __float_as_uint(m.y));
                    atomicMax(&gp[2], __float_as_uint(m.z));
                    atomicMax(&gp[3], __float_as_uint(m.w));
                }
                curg = g; m = v;
            } else {
                m.x = fmaxf(m.x, v.x); m.y = fmaxf(m.y, v.y);
                m.z = fmaxf(m.z, v.z); m.w = fmaxf(m.w, v.w);
            }
        }
        if (curg >= 0) {
            unsigned* gp = &gmax[(size_t)curg * 256 + f0];
            atomicMax(&gp[0], __float_as_uint(m.x));
            atomicMax(&gp[1], __float_as_uint(m.y));
            atomicMax(&gp[2], __float_as_uint(m.z));
            atomicMax(&gp[3], __float_as_uint(m.w));
        }
    }
}

// ---------------- MLP head (4 graphs/block: W amortized) ----------------

__global__ __launch_bounds__(256) void k_gemm3(const float* __restrict__ A,
    const float* __restrict__ W, const float* __restrict__ bias,
    float* __restrict__ out) {
    __shared__ float rs[4][256];
    int b = blockIdx.x, tid = threadIdx.x;    // 128 blocks
#pragma unroll
    for (int g = 0; g < 4; g++) rs[g][tid] = A[(b * 4 + g) * 256 + tid];
    __syncthreads();
    float acc[4][4];
#pragma unroll
    for (int g = 0; g < 4; g++)
#pragma unroll
        for (int j = 0; j < 4; j++) acc[g][j] = 0.f;
    for (int k = 0; k < 256; k++) {
        float w0 = W[k * 1024 + tid];
        float w1 = W[k * 1024 + tid + 256];
        float w2 = W[k * 1024 + tid + 512];
        float w3 = W[k * 1024 + tid + 768];
#pragma unroll
        for (int g = 0; g < 4; g++) {
            float a = rs[g][k];
            acc[g][0] += a * w0; acc[g][1] += a * w1;
            acc[g][2] += a * w2; acc[g][3] += a * w3;
        }
    }
#pragma unroll
    for (int g = 0; g < 4; g++)
#pragma unroll
        for (int j = 0; j < 4; j++) {
            int f = tid + j * 256;
            out[(b * 4 + g) * 1024 + f] = fmaxf(acc[g][j] + bias[f], 0.0f);
        }
}

__global__ __launch_bounds__(128) void k_gemm4(const float* __restrict__ A,
    const float* __restrict__ W, const float* __restrict__ bias,
    float* __restrict__ out) {
    __shared__ float rs[4][1024];   // 16 KB
    int b = blockIdx.x, tid = threadIdx.x;    // 128 blocks
    for (int i = tid; i < 4096; i += 128) rs[i >> 10][i & 1023] = A[b * 4096 + i];
    __syncthreads();
    float acc[4] = {0.f, 0.f, 0.f, 0.f};
    for (int k = 0; k < 1024; k++) {
        float wv = W[k * 128 + tid];
#pragma unroll
        for (int g = 0; g < 4; g++) acc[g] += rs[g][k] * wv;
    }
#pragma unroll
    for (int g = 0; g < 4; g++)
        out[(b * 4 + g) * 128 + tid] = acc[g] + bias[tid];
}

extern "C" void kernel_launch(void* const* d_in, const int* in_sizes, int n_in,
                              void* d_out, int out_size, void* d_ws, size_t ws_size,
                              hipStream_t stream) {
    const float* x    = (const float*)d_in[0];
    const int*   ei   = (const int*)d_in[1];
    const int*   batch= (const int*)d_in[2];
    const float* W1   = (const float*)d_in[3];
    const float* b1   = (const float*)d_in[4];
    const float* W2   = (const float*)d_in[5];
    const float* b2   = (const float*)d_in[6];
    const float* Wg1  = (const float*)d_in[7];
    const float* bg1  = (const float*)d_in[8];
    const float* Wg2  = (const float*)d_in[9];
    const float* bg2  = (const float*)d_in[10];
    const int* src = ei;
    const int* dst = ei + NE;

    char* w8 = (char*)d_ws;
    int*   cnt     = (int*)w8;                 w8 += (size_t)NN * 4;
    int*   row_ptr = (int*)w8;                 w8 += (size_t)(NN + 4) * 4;
    int*   cursor  = (int*)w8;                 w8 += (size_t)NN * 4;
    int*   bsum    = (int*)w8;                 w8 += 128 * 4;
    int2*  es      = (int2*)w8;                w8 += (size_t)NE * 8;
    float* dinv    = (float*)w8;               w8 += (size_t)NN * 4;
    float* h1      = (float*)w8;               w8 += (size_t)NN * 128 * 4;
    unsigned* gmax = (unsigned*)w8;            w8 += (size_t)NG * 256 * 4;
    float* g1      = (float*)w8;               w8 += (size_t)NG * 1024 * 4;

    // CSR build
    hipMemsetAsync(cnt, 0, (size_t)NN * 4, stream);
    k_hist<<<(NE + 255) / 256, 256, 0, stream>>>(dst, cnt, NE);
    k_prep<<<(NG * 256 + 255) / 256, 256, 0, stream>>>(cnt, dinv, (float*)gmax);
    k_bsum<<<NBLK, 256, 0, stream>>>(cnt, bsum);
    k_scan_bsum<<<1, 128, 0, stream>>>(bsum, row_ptr);
    k_scan_blocks<<<NBLK, 256, 0, stream>>>(cnt, bsum, row_ptr, cursor);
    k_fillslots<<<(NE + 255) / 256, 256, 0, stream>>>(src, dst, dinv, cursor, es, NE);

    // layer 1 (fused pair-zip gather + gemm + relu): 6250 workers x 16 nodes
    k_fused1<<<1563, 256, 0, stream>>>(x, row_ptr, es, dinv, W1, b1, h1);

    // layer 2 (fused pair-zip gather + gemm + relu + pool)
    k_fused2<<<1563, 256, 0, stream>>>(h1, row_ptr, es, dinv, W2, b2, batch, gmax);

    // MLP head
    k_gemm3<<<NG / 4, 256, 0, stream>>>((const float*)gmax, Wg1, bg1, g1);
    k_gemm4<<<NG / 4, 128, 0, stream>>>(g1, Wg2, bg2, (float*)d_out);
}

// Round 7
// 580.864 us; speedup vs baseline: 1.5683x; 1.5683x over previous
//
#include <hip/hip_runtime.h>
#include <hip/hip_fp16.h>

// GCN forward, CSR-gather, fused gather+GEMM (R4 structure: pair-zip, 4
// waves/block, 8 nodes/wave, VGPR-lean) + FP16 h1: layer-2's random gather
// traffic halves (512B -> 256B rows). R6 lesson: occupancy (not manual
// prefetch) is the concurrency engine -- keep VGPR ~40, never spend registers
// on software pipelines the compiler will serialize anyway.
// MLP head: 4 graphs/block (W amortized). cnt zeroed via memset.

#define NN 100000
#define NE 1600000
#define NG 512
#define NBLK ((NN + 1023) / 1024)   // 98 scan blocks

typedef float v2f __attribute__((ext_vector_type(2)));

// ---------------- CSR build (counting sort by dst) ----------------

__global__ void k_hist(const int* __restrict__ dst, int* cnt, int e) {
    int i = blockIdx.x * blockDim.x + threadIdx.x;
    if (i < e) atomicAdd(&cnt[dst[i]], 1);
}

// fused: dinv[i] = rsqrt(cnt[i]+1)  and  gmax zero-init (NG*256 = 131072)
__global__ void k_prep(const int* __restrict__ cnt, float* __restrict__ dinv,
                       float* __restrict__ gmax) {
    int i = blockIdx.x * blockDim.x + threadIdx.x;
    if (i < NN) dinv[i] = rsqrtf((float)cnt[i] + 1.0f);
    if (i < NG * 256) gmax[i] = 0.0f;
}

__global__ __launch_bounds__(256) void k_bsum(const int* __restrict__ cnt, int* __restrict__ bsum) {
    __shared__ int s[256];
    int b = blockIdx.x, t = threadIdx.x;
    int base = b * 1024 + t * 4;
    int v = 0;
#pragma unroll
    for (int j = 0; j < 4; j++) { int i = base + j; if (i < NN) v += cnt[i]; }
    s[t] = v; __syncthreads();
    for (int off = 128; off > 0; off >>= 1) {
        if (t < off) s[t] += s[t + off];
        __syncthreads();
    }
    if (t == 0) bsum[b] = s[0];
}

__global__ __launch_bounds__(128) void k_scan_bsum(int* bsum, int* row_ptr) {
    __shared__ int s[128];
    int t = threadIdx.x;
    int v = (t < NBLK) ? bsum[t] : 0;
    s[t] = v; __syncthreads();
    for (int off = 1; off < 128; off <<= 1) {
        int u = (t >= off) ? s[t - off] : 0;
        __syncthreads();
        s[t] += u;
        __syncthreads();
    }
    if (t < NBLK) bsum[t] = s[t] - v;
    if (t == 0) row_ptr[NN] = NE;
}

__global__ __launch_bounds__(256) void k_scan_blocks(const int* __restrict__ cnt,
    const int* __restrict__ bsum, int* __restrict__ row_ptr, int* __restrict__ cursor) {
    __shared__ int s[256];
    int b = blockIdx.x, t = threadIdx.x;
    int base = b * 1024 + t * 4;
    int v[4]; int sum = 0;
#pragma unroll
    for (int j = 0; j < 4; j++) { int i = base + j; v[j] = (i < NN) ? cnt[i] : 0; sum += v[j]; }
    s[t] = sum; __syncthreads();
    for (int off = 1; off < 256; off <<= 1) {
        int u = (t >= off) ? s[t - off] : 0;
        __syncthreads();
        s[t] += u;
        __syncthreads();
    }
    int excl = s[t] - sum + bsum[b];
#pragma unroll
    for (int j = 0; j < 4; j++) {
        int i = base + j;
        if (i < NN) { row_ptr[i] = excl; cursor[i] = excl; excl += v[j]; }
    }
}

// counting-sort fill: one packed 8B store per edge: es[pos] = {src, w}
__global__ void k_fillslots(const int* __restrict__ src, const int* __restrict__ dst,
    const float* __restrict__ dinv, int* cursor, int2* __restrict__ es, int e) {
    int i = blockIdx.x * blockDim.x + threadIdx.x;
    if (i >= e) return;
    int s = src[i], d = dst[i];
    int pos = atomicAdd(&cursor[d], 1);
    es[pos] = make_int2(s, __float_as_int(dinv[s] * dinv[d]));
}

// ---------------- fused1: pair-zip gather78 + gemm1 -> fp16 h1 ----------------
// 4 waves/block, wave owns 8 nodes (4 pairs). Gather lanes 0..38 (float2).
// GEMM: lane covers 2 of 128 out-feats; A wave-uniform LDS broadcast; W1 rows
// coalesced from L1/L2. relu -> h1 stored as __half2 (4B/lane coalesced).
__global__ __launch_bounds__(256) void k_fused1(const float* __restrict__ x,
    const int* __restrict__ rp, const int2* __restrict__ es,
    const float* __restrict__ dinv, const float* __restrict__ W,
    const float* __restrict__ bias, __half* __restrict__ out) {
    __shared__ float As[4][8][80];   // 10 KB
    int tid = threadIdx.x;
    int wv = tid >> 6, l = tid & 63;
    int task = __builtin_amdgcn_readfirstlane(blockIdx.x * 4 + wv);  // 12500 tasks
    int n0 = task * 8;
    if (n0 >= NN) return;

    if (l < 39) {
        for (int pi = 0; pi < 4; pi++) {
            int nA = n0 + 2 * pi, nB = nA + 1;
            float diA = dinv[nA], swA = diA * diA;
            float diB = dinv[nB], swB = diB * diB;
            float2 aA = ((const float2*)(x + (size_t)nA * 78))[l];
            float2 aB = ((const float2*)(x + (size_t)nB * 78))[l];
            aA.x *= swA; aA.y *= swA;
            aB.x *= swB; aB.y *= swB;
            int eA = rp[nA], eA1 = rp[nA + 1];
            int eB = rp[nB], eB1 = rp[nB + 1];
            int cA = (eA1 - eA) >> 3, cB = (eB1 - eB) >> 3;
            while (cA > 0 || cB > 0) {
                bool dA = (cA > 0), dB = (cB > 0);
                int2 esA[8], esB[8];
                float2 vA[8], vB[8];
                if (dA) {
#pragma unroll
                    for (int j = 0; j < 8; j++) esA[j] = es[eA + j];
                }
                if (dB) {
#pragma unroll
                    for (int j = 0; j < 8; j++) esB[j] = es[eB + j];
                }
                if (dA) {
#pragma unroll
                    for (int j = 0; j < 8; j++)
                        vA[j] = ((const float2*)(x + (size_t)esA[j].x * 78))[l];
                }
                if (dB) {
#pragma unroll
                    for (int j = 0; j < 8; j++)
                        vB[j] = ((const float2*)(x + (size_t)esB[j].x * 78))[l];
                }
                if (dA) {
#pragma unroll
                    for (int j = 0; j < 8; j++) {
                        float w = __int_as_float(esA[j].y);
                        aA.x += vA[j].x * w; aA.y += vA[j].y * w;
                    }
                    eA += 8; cA--;
                }
                if (dB) {
#pragma unroll
                    for (int j = 0; j < 8; j++) {
                        float w = __int_as_float(esB[j].y);
                        aB.x += vB[j].x * w; aB.y += vB[j].y * w;
                    }
                    eB += 8; cB--;
                }
            }
            while (eA < eA1 && eB < eB1) {
                int2 pA = es[eA], pB = es[eB];
                float2 vA2 = ((const float2*)(x + (size_t)pA.x * 78))[l];
                float2 vB2 = ((const float2*)(x + (size_t)pB.x * 78))[l];
                float wA = __int_as_float(pA.y), wB = __int_as_float(pB.y);
                aA.x += vA2.x * wA; aA.y += vA2.y * wA;
                aB.x += vB2.x * wB; aB.y += vB2.y * wB;
                eA++; eB++;
            }
            for (; eA < eA1; eA++) {
                int2 p = es[eA];
                float w = __int_as_float(p.y);
                float2 v = ((const float2*)(x + (size_t)p.x * 78))[l];
                aA.x += v.x * w; aA.y += v.y * w;
            }
            for (; eB < eB1; eB++) {
                int2 p = es[eB];
                float w = __int_as_float(p.y);
                float2 v = ((const float2*)(x + (size_t)p.x * 78))[l];
                aB.x += v.x * w; aB.y += v.y * w;
            }
            *(float2*)&As[wv][2 * pi][2 * l] = aA;
            *(float2*)&As[wv][2 * pi + 1][2 * l] = aB;
        }
    }
    // same-wave producer/consumer: compiler inserts lgkmcnt waits; no barrier.

    int f0 = l * 2;
    float2 acc[8];
#pragma unroll
    for (int i = 0; i < 8; i++) acc[i] = make_float2(0.f, 0.f);

    for (int k = 0; k < 76; k += 4) {
        float2 w0 = *(const float2*)&W[(k + 0) * 128 + f0];
        float2 w1 = *(const float2*)&W[(k + 1) * 128 + f0];
        float2 w2 = *(const float2*)&W[(k + 2) * 128 + f0];
        float2 w3 = *(const float2*)&W[(k + 3) * 128 + f0];
#pragma unroll
        for (int i = 0; i < 8; i++) {
            float4 a = *(const float4*)&As[wv][i][k];
            acc[i].x += a.x * w0.x + a.y * w1.x + a.z * w2.x + a.w * w3.x;
            acc[i].y += a.x * w0.y + a.y * w1.y + a.z * w2.y + a.w * w3.y;
        }
    }
    {   // rows 76,77
        float2 w0 = *(const float2*)&W[76 * 128 + f0];
        float2 w1 = *(const float2*)&W[77 * 128 + f0];
#pragma unroll
        for (int i = 0; i < 8; i++) {
            float2 a = *(const float2*)&As[wv][i][76];
            acc[i].x += a.x * w0.x + a.y * w1.x;
            acc[i].y += a.x * w0.y + a.y * w1.y;
        }
    }
    float2 bv = *(const float2*)&bias[f0];
#pragma unroll
    for (int i = 0; i < 8; i++) {
        float ox = fmaxf(acc[i].x + bv.x, 0.f);
        float oy = fmaxf(acc[i].y + bv.y, 0.f);
        *(__half2*)&out[(size_t)(n0 + i) * 128 + f0] = __floats2half2_rn(ox, oy);
    }
}

// ---------------- fused2: pair-zip fp16 gather128 + gemm2(pk_fma) + pool ----------------
// 4 waves/block, wave owns 8 nodes (4 pairs); all 64 lanes gather (__half2 =
// 4B/lane, 256B rows -> HALF the random-gather traffic). GEMM: lane covers
// 4 of 256 out-feats, packed-f32 fma; pool: flush-on-change segment-max.
__global__ __launch_bounds__(256) void k_fused2(const __half* __restrict__ h,
    const int* __restrict__ rp, const int2* __restrict__ es,
    const float* __restrict__ dinv, const float* __restrict__ W,
    const float* __restrict__ bias, const int* __restrict__ batch,
    unsigned* __restrict__ gmax) {
    __shared__ float As[4][8][128];  // 16 KB
    int tid = threadIdx.x;
    int wv = tid >> 6, l = tid & 63;
    int task = __builtin_amdgcn_readfirstlane(blockIdx.x * 4 + wv);  // 12500 tasks
    int n0 = task * 8;
    if (n0 >= NN) return;

    for (int pi = 0; pi < 4; pi++) {
        int nA = n0 + 2 * pi, nB = nA + 1;
        float diA = dinv[nA], swA = diA * diA;
        float diB = dinv[nB], swB = diB * diB;
        float2 aA = __half22float2(((const __half2*)(h + (size_t)nA * 128))[l]);
        float2 aB = __half22float2(((const __half2*)(h + (size_t)nB * 128))[l]);
        aA.x *= swA; aA.y *= swA;
        aB.x *= swB; aB.y *= swB;
        int eA = rp[nA], eA1 = rp[nA + 1];
        int eB = rp[nB], eB1 = rp[nB + 1];
        int cA = (eA1 - eA) >> 3, cB = (eB1 - eB) >> 3;
        while (cA > 0 || cB > 0) {
            bool dA = (cA > 0), dB = (cB > 0);
            int2 esA[8], esB[8];
            __half2 vA[8], vB[8];
            if (dA) {
#pragma unroll
                for (int j = 0; j < 8; j++) esA[j] = es[eA + j];
            }
            if (dB) {
#pragma unroll
                for (int j = 0; j < 8; j++) esB[j] = es[eB + j];
            }
            if (dA) {
#pragma unroll
                for (int j = 0; j < 8; j++)
                    vA[j] = ((const __half2*)(h + (size_t)esA[j].x * 128))[l];
            }
            if (dB) {
#pragma unroll
                for (int j = 0; j < 8; j++)
                    vB[j] = ((const __half2*)(h + (size_t)esB[j].x * 128))[l];
            }
            if (dA) {
#pragma unroll
                for (int j = 0; j < 8; j++) {
                    float w = __int_as_float(esA[j].y);
                    float2 v = __half22float2(vA[j]);
                    aA.x += v.x * w; aA.y += v.y * w;
                }
                eA += 8; cA--;
            }
            if (dB) {
#pragma unroll
                for (int j = 0; j < 8; j++) {
                    float w = __int_as_float(esB[j].y);
                    float2 v = __half22float2(vB[j]);
                    aB.x += v.x * w; aB.y += v.y * w;
                }
                eB += 8; cB--;
            }
        }
        while (eA < eA1 && eB < eB1) {
            int2 pA = es[eA], pB = es[eB];
            float2 vA2 = __half22float2(((const __half2*)(h + (size_t)pA.x * 128))[l]);
            float2 vB2 = __half22float2(((const __half2*)(h + (size_t)pB.x * 128))[l]);
            float wA = __int_as_float(pA.y), wB = __int_as_float(pB.y);
            aA.x += vA2.x * wA; aA.y += vA2.y * wA;
            aB.x += vB2.x * wB; aB.y += vB2.y * wB;
            eA++; eB++;
        }
        for (; eA < eA1; eA++) {
            int2 p = es[eA];
            float w = __int_as_float(p.y);
            float2 v = __half22float2(((const __half2*)(h + (size_t)p.x * 128))[l]);
            aA.x += v.x * w; aA.y += v.y * w;
        }
        for (; eB < eB1; eB++) {
            int2 p = es[eB];
            float w = __int_as_float(p.y);
            float2 v = __half22float2(((const __half2*)(h + (size_t)p.x * 128))[l]);
            aB.x += v.x * w; aB.y += v.y * w;
        }
        *(float2*)&As[wv][2 * pi][2 * l] = aA;
        *(float2*)&As[wv][2 * pi + 1][2 * l] = aB;
    }
    // same-wave producer/consumer: no barrier needed.

    int f0 = l * 4;
    v2f acc[8][2];
#pragma unroll
    for (int i = 0; i < 8; i++) { acc[i][0] = (v2f)(0.f); acc[i][1] = (v2f)(0.f); }

    for (int k = 0; k < 128; k += 4) {
        float4 w0 = *(const float4*)&W[(size_t)(k + 0) * 256 + f0];
        float4 w1 = *(const float4*)&W[(size_t)(k + 1) * 256 + f0];
        float4 w2 = *(const float4*)&W[(size_t)(k + 2) * 256 + f0];
        float4 w3 = *(const float4*)&W[(size_t)(k + 3) * 256 + f0];
        v2f w0a = {w0.x, w0.y}, w0b = {w0.z, w0.w};
        v2f w1a = {w1.x, w1.y}, w1b = {w1.z, w1.w};
        v2f w2a = {w2.x, w2.y}, w2b = {w2.z, w2.w};
        v2f w3a = {w3.x, w3.y}, w3b = {w3.z, w3.w};
#pragma unroll
        for (int i = 0; i < 8; i++) {
            float4 a = *(const float4*)&As[wv][i][k];
            v2f sx = {a.x, a.x}, sy = {a.y, a.y}, sz = {a.z, a.z}, sw = {a.w, a.w};
            acc[i][0] = __builtin_elementwise_fma(sx, w0a, acc[i][0]);
            acc[i][1] = __builtin_elementwise_fma(sx, w0b, acc[i][1]);
            acc[i][0] = __builtin_elementwise_fma(sy, w1a, acc[i][0]);
            acc[i][1] = __builtin_elementwise_fma(sy, w1b, acc[i][1]);
            acc[i][0] = __builtin_elementwise_fma(sz, w2a, acc[i][0]);
            acc[i][1] = __builtin_elementwise_fma(sz, w2b, acc[i][1]);
            acc[i][0] = __builtin_elementwise_fma(sw, w3a, acc[i][0]);
            acc[i][1] = __builtin_elementwise_fma(sw, w3b, acc[i][1]);
        }
    }

    float4 bv = *(const float4*)&bias[f0];
    int curg = -1;
    float4 m = make_float4(0.f, 0.f, 0.f, 0.f);
#pragma unroll
    for (int i = 0; i < 8; i++) {
        int g = batch[n0 + i];
        float4 v;
        v.x = fmaxf(acc[i][0].x + bv.x, 0.f); v.y = fmaxf(acc[i][0].y + bv.y, 0.f);
        v.z = fmaxf(acc[i][1].x + bv.z, 0.f); v.w = fmaxf(acc[i][1].y + bv.w, 0.f);
        if (g != curg) {
            if (curg >= 0) {
                unsigned* gp = &gmax[(size_t)curg * 256 + f0];
                atomicMax(&gp[0], __float_as_uint(m.x));
                atomicMax(&gp[1], __float_as_uint(m.y));
                atomicMax(&gp[2], __float_as_uint(m.z));
                atomicMax(&gp[3], __float_as_uint(m.w));
            }
            curg = g; m = v;
        } else {
            m.x = fmaxf(m.x, v.x); m.y = fmaxf(m.y, v.y);
            m.z = fmaxf(m.z, v.z); m.w = fmaxf(m.w, v.w);
        }
    }
    if (curg >= 0) {
        unsigned* gp = &gmax[(size_t)curg * 256 + f0];
        atomicMax(&gp[0], __float_as_uint(m.x));
        atomicMax(&gp[1], __float_as_uint(m.y));
        atomicMax(&gp[2], __float_as_uint(m.z));
        atomicMax(&gp[3], __float_as_uint(m.w));
    }
}

// ---------------- MLP head (4 graphs/block: W amortized) ----------------

__global__ __launch_bounds__(256) void k_gemm3(const float* __restrict__ A,
    const float* __restrict__ W, const float* __restrict__ bias,
    float* __restrict__ out) {
    __shared__ float rs[4][256];
    int b = blockIdx.x, tid = threadIdx.x;    // 128 blocks
#pragma unroll
    for (int g = 0; g < 4; g++) rs[g][tid] = A[(b * 4 + g) * 256 + tid];
    __syncthreads();
    float acc[4][4];
#pragma unroll
    for (int g = 0; g < 4; g++)
#pragma unroll
        for (int j = 0; j < 4; j++) acc[g][j] = 0.f;
    for (int k = 0; k < 256; k++) {
        float w0 = W[k * 1024 + tid];
        float w1 = W[k * 1024 + tid + 256];
        float w2 = W[k * 1024 + tid + 512];
        float w3 = W[k * 1024 + tid + 768];
#pragma unroll
        for (int g = 0; g < 4; g++) {
            float a = rs[g][k];
            acc[g][0] += a * w0; acc[g][1] += a * w1;
            acc[g][2] += a * w2; acc[g][3] += a * w3;
        }
    }
#pragma unroll
    for (int g = 0; g < 4; g++)
#pragma unroll
        for (int j = 0; j < 4; j++) {
            int f = tid + j * 256;
            out[(b * 4 + g) * 1024 + f] = fmaxf(acc[g][j] + bias[f], 0.0f);
        }
}

__global__ __launch_bounds__(128) void k_gemm4(const float* __restrict__ A,
    const float* __restrict__ W, const float* __restrict__ bias,
    float* __restrict__ out) {
    __shared__ float rs[4][1024];   // 16 KB
    int b = blockIdx.x, tid = threadIdx.x;    // 128 blocks
    for (int i = tid; i < 4096; i += 128) rs[i >> 10][i & 1023] = A[b * 4096 + i];
    __syncthreads();
    float acc[4] = {0.f, 0.f, 0.f, 0.f};
    for (int k = 0; k < 1024; k++) {
        float wv = W[k * 128 + tid];
#pragma unroll
        for (int g = 0; g < 4; g++) acc[g] += rs[g][k] * wv;
    }
#pragma unroll
    for (int g = 0; g < 4; g++)
        out[(b * 4 + g) * 128 + tid] = acc[g] + bias[tid];
}

extern "C" void kernel_launch(void* const* d_in, const int* in_sizes, int n_in,
                              void* d_out, int out_size, void* d_ws, size_t ws_size,
                              hipStream_t stream) {
    const float* x    = (const float*)d_in[0];
    const int*   ei   = (const int*)d_in[1];
    const int*   batch= (const int*)d_in[2];
    const float* W1   = (const float*)d_in[3];
    const float* b1   = (const float*)d_in[4];
    const float* W2   = (const float*)d_in[5];
    const float* b2   = (const float*)d_in[6];
    const float* Wg1  = (const float*)d_in[7];
    const float* bg1  = (const float*)d_in[8];
    const float* Wg2  = (const float*)d_in[9];
    const float* bg2  = (const float*)d_in[10];
    const int* src = ei;
    const int* dst = ei + NE;

    char* w8 = (char*)d_ws;
    int*   cnt     = (int*)w8;                 w8 += (size_t)NN * 4;
    int*   row_ptr = (int*)w8;                 w8 += (size_t)(NN + 4) * 4;
    int*   cursor  = (int*)w8;                 w8 += (size_t)NN * 4;
    int*   bsum    = (int*)w8;                 w8 += 128 * 4;
    int2*  es      = (int2*)w8;                w8 += (size_t)NE * 8;
    float* dinv    = (float*)w8;               w8 += (size_t)NN * 4;
    __half* h1     = (__half*)w8;              w8 += (size_t)NN * 128 * 2;
    unsigned* gmax = (unsigned*)w8;            w8 += (size_t)NG * 256 * 4;
    float* g1      = (float*)w8;               w8 += (size_t)NG * 1024 * 4;

    // CSR build
    hipMemsetAsync(cnt, 0, (size_t)NN * 4, stream);
    k_hist<<<(NE + 255) / 256, 256, 0, stream>>>(dst, cnt, NE);
    k_prep<<<(NG * 256 + 255) / 256, 256, 0, stream>>>(cnt, dinv, (float*)gmax);
    k_bsum<<<NBLK, 256, 0, stream>>>(cnt, bsum);
    k_scan_bsum<<<1, 128, 0, stream>>>(bsum, row_ptr);
    k_scan_blocks<<<NBLK, 256, 0, stream>>>(cnt, bsum, row_ptr, cursor);
    k_fillslots<<<(NE + 255) / 256, 256, 0, stream>>>(src, dst, dinv, cursor, es, NE);

    // layer 1 (fused pair-zip gather + gemm + relu -> fp16 h1)
    k_fused1<<<NN / 32, 256, 0, stream>>>(x, row_ptr, es, dinv, W1, b1, h1);

    // layer 2 (fused pair-zip fp16 gather + gemm + relu + pool)
    k_fused2<<<NN / 32, 256, 0, stream>>>(h1, row_ptr, es, dinv, W2, b2, batch, gmax);

    // MLP head
    k_gemm3<<<NG / 4, 256, 0, stream>>>((const float*)gmax, Wg1, bg1, g1);
    k_gemm4<<<NG / 4, 128, 0, stream>>>(g1, Wg2, bg2, (float*)d_out);
}

// Round 8
// 578.302 us; speedup vs baseline: 1.5752x; 1.0044x over previous
//
#include <hip/hip_runtime.h>
#include <hip/hip_fp16.h>

// GCN forward, CSR-gather, fused gather+GEMM (R4 structure: pair-zip, 4
// waves/block, 8 nodes/wave, VGPR-lean ~40) + FP16 GATHER TRAFFIC both layers:
//   layer1: x pre-converted to fp16 xh (one 47MB pass) -> 156B rows
//   layer2: h1 stored fp16 -> 256B rows
// R7 evidence: fp16 rows cut fused2 200->158us (FETCH 500->280MB). fused1
// carries the same 500MB fp32 x-gather -> same lever. GEMMs stay packed-fp32
// FMA (already ~76% of fp32 peak; dot2 is same inst rate, no gain).
// MLP head: gemm3 8 graphs/block, gemm4 4 graphs/block. cnt via memset.

#define NN 100000
#define NE 1600000
#define NG 512
#define NBLK ((NN + 1023) / 1024)   // 98 scan blocks

typedef float v2f __attribute__((ext_vector_type(2)));

// ---------------- CSR build (counting sort by dst) ----------------

__global__ void k_hist(const int* __restrict__ dst, int* cnt, int e) {
    int i = blockIdx.x * blockDim.x + threadIdx.x;
    if (i < e) atomicAdd(&cnt[dst[i]], 1);
}

// fused: dinv[i] = rsqrt(cnt[i]+1)  and  gmax zero-init (NG*256 = 131072)
__global__ void k_prep(const int* __restrict__ cnt, float* __restrict__ dinv,
                       float* __restrict__ gmax) {
    int i = blockIdx.x * blockDim.x + threadIdx.x;
    if (i < NN) dinv[i] = rsqrtf((float)cnt[i] + 1.0f);
    if (i < NG * 256) gmax[i] = 0.0f;
}

// x [NN][78] fp32 -> xh [NN][78] fp16 (3.9M half2 elements)
__global__ void k_cvt_x(const float* __restrict__ x, __half* __restrict__ xh) {
    int i = blockIdx.x * blockDim.x + threadIdx.x;
    if (i < NN * 39) {
        float2 v = ((const float2*)x)[i];
        ((__half2*)xh)[i] = __floats2half2_rn(v.x, v.y);
    }
}

__global__ __launch_bounds__(256) void k_bsum(const int* __restrict__ cnt, int* __restrict__ bsum) {
    __shared__ int s[256];
    int b = blockIdx.x, t = threadIdx.x;
    int base = b * 1024 + t * 4;
    int v = 0;
#pragma unroll
    for (int j = 0; j < 4; j++) { int i = base + j; if (i < NN) v += cnt[i]; }
    s[t] = v; __syncthreads();
    for (int off = 128; off > 0; off >>= 1) {
        if (t < off) s[t] += s[t + off];
        __syncthreads();
    }
    if (t == 0) bsum[b] = s[0];
}

__global__ __launch_bounds__(128) void k_scan_bsum(int* bsum, int* row_ptr) {
    __shared__ int s[128];
    int t = threadIdx.x;
    int v = (t < NBLK) ? bsum[t] : 0;
    s[t] = v; __syncthreads();
    for (int off = 1; off < 128; off <<= 1) {
        int u = (t >= off) ? s[t - off] : 0;
        __syncthreads();
        s[t] += u;
        __syncthreads();
    }
    if (t < NBLK) bsum[t] = s[t] - v;
    if (t == 0) row_ptr[NN] = NE;
}

__global__ __launch_bounds__(256) void k_scan_blocks(const int* __restrict__ cnt,
    const int* __restrict__ bsum, int* __restrict__ row_ptr, int* __restrict__ cursor) {
    __shared__ int s[256];
    int b = blockIdx.x, t = threadIdx.x;
    int base = b * 1024 + t * 4;
    int v[4]; int sum = 0;
#pragma unroll
    for (int j = 0; j < 4; j++) { int i = base + j; v[j] = (i < NN) ? cnt[i] : 0; sum += v[j]; }
    s[t] = sum; __syncthreads();
    for (int off = 1; off < 256; off <<= 1) {
        int u = (t >= off) ? s[t - off] : 0;
        __syncthreads();
        s[t] += u;
        __syncthreads();
    }
    int excl = s[t] - sum + bsum[b];
#pragma unroll
    for (int j = 0; j < 4; j++) {
        int i = base + j;
        if (i < NN) { row_ptr[i] = excl; cursor[i] = excl; excl += v[j]; }
    }
}

// counting-sort fill: one packed 8B store per edge: es[pos] = {src, w}
__global__ void k_fillslots(const int* __restrict__ src, const int* __restrict__ dst,
    const float* __restrict__ dinv, int* cursor, int2* __restrict__ es, int e) {
    int i = blockIdx.x * blockDim.x + threadIdx.x;
    if (i >= e) return;
    int s = src[i], d = dst[i];
    int pos = atomicAdd(&cursor[d], 1);
    es[pos] = make_int2(s, __float_as_int(dinv[s] * dinv[d]));
}

// ---------------- fused1: pair-zip fp16 gather78 + gemm1 -> fp16 h1 ----------------
// 4 waves/block, wave owns 8 nodes (4 pairs). Gather lanes 0..38 (__half2 =
// 4B/lane, 156B rows). GEMM: lane covers 2 of 128 out-feats; A via LDS
// broadcast (fp32); W1 rows from L1/L2. relu -> h1 fp16.
__global__ __launch_bounds__(256) void k_fused1(const __half* __restrict__ x,
    const int* __restrict__ rp, const int2* __restrict__ es,
    const float* __restrict__ dinv, const float* __restrict__ W,
    const float* __restrict__ bias, __half* __restrict__ out) {
    __shared__ float As[4][8][80];   // 10 KB
    int tid = threadIdx.x;
    int wv = tid >> 6, l = tid & 63;
    int task = __builtin_amdgcn_readfirstlane(blockIdx.x * 4 + wv);  // 12500 tasks
    int n0 = task * 8;
    if (n0 >= NN) return;

    if (l < 39) {
        for (int pi = 0; pi < 4; pi++) {
            int nA = n0 + 2 * pi, nB = nA + 1;
            float diA = dinv[nA], swA = diA * diA;
            float diB = dinv[nB], swB = diB * diB;
            float2 aA = __half22float2(((const __half2*)(x + (size_t)nA * 78))[l]);
            float2 aB = __half22float2(((const __half2*)(x + (size_t)nB * 78))[l]);
            aA.x *= swA; aA.y *= swA;
            aB.x *= swB; aB.y *= swB;
            int eA = rp[nA], eA1 = rp[nA + 1];
            int eB = rp[nB], eB1 = rp[nB + 1];
            int cA = (eA1 - eA) >> 3, cB = (eB1 - eB) >> 3;
            while (cA > 0 || cB > 0) {
                bool dA = (cA > 0), dB = (cB > 0);
                int2 esA[8], esB[8];
                __half2 vA[8], vB[8];
                if (dA) {
#pragma unroll
                    for (int j = 0; j < 8; j++) esA[j] = es[eA + j];
                }
                if (dB) {
#pragma unroll
                    for (int j = 0; j < 8; j++) esB[j] = es[eB + j];
                }
                if (dA) {
#pragma unroll
                    for (int j = 0; j < 8; j++)
                        vA[j] = ((const __half2*)(x + (size_t)esA[j].x * 78))[l];
                }
                if (dB) {
#pragma unroll
                    for (int j = 0; j < 8; j++)
                        vB[j] = ((const __half2*)(x + (size_t)esB[j].x * 78))[l];
                }
                if (dA) {
#pragma unroll
                    for (int j = 0; j < 8; j++) {
                        float w = __int_as_float(esA[j].y);
                        float2 v = __half22float2(vA[j]);
                        aA.x += v.x * w; aA.y += v.y * w;
                    }
                    eA += 8; cA--;
                }
                if (dB) {
#pragma unroll
                    for (int j = 0; j < 8; j++) {
                        float w = __int_as_float(esB[j].y);
                        float2 v = __half22float2(vB[j]);
                        aB.x += v.x * w; aB.y += v.y * w;
                    }
                    eB += 8; cB--;
                }
            }
            while (eA < eA1 && eB < eB1) {
                int2 pA = es[eA], pB = es[eB];
                float2 vA2 = __half22float2(((const __half2*)(x + (size_t)pA.x * 78))[l]);
                float2 vB2 = __half22float2(((const __half2*)(x + (size_t)pB.x * 78))[l]);
                float wA = __int_as_float(pA.y), wB = __int_as_float(pB.y);
                aA.x += vA2.x * wA; aA.y += vA2.y * wA;
                aB.x += vB2.x * wB; aB.y += vB2.y * wB;
                eA++; eB++;
            }
            for (; eA < eA1; eA++) {
                int2 p = es[eA];
                float w = __int_as_float(p.y);
                float2 v = __half22float2(((const __half2*)(x + (size_t)p.x * 78))[l]);
                aA.x += v.x * w; aA.y += v.y * w;
            }
            for (; eB < eB1; eB++) {
                int2 p = es[eB];
                float w = __int_as_float(p.y);
                float2 v = __half22float2(((const __half2*)(x + (size_t)p.x * 78))[l]);
                aB.x += v.x * w; aB.y += v.y * w;
            }
            *(float2*)&As[wv][2 * pi][2 * l] = aA;
            *(float2*)&As[wv][2 * pi + 1][2 * l] = aB;
        }
    }
    // same-wave producer/consumer: compiler inserts lgkmcnt waits; no barrier.

    int f0 = l * 2;
    float2 acc[8];
#pragma unroll
    for (int i = 0; i < 8; i++) acc[i] = make_float2(0.f, 0.f);

    for (int k = 0; k < 76; k += 4) {
        float2 w0 = *(const float2*)&W[(k + 0) * 128 + f0];
        float2 w1 = *(const float2*)&W[(k + 1) * 128 + f0];
        float2 w2 = *(const float2*)&W[(k + 2) * 128 + f0];
        float2 w3 = *(const float2*)&W[(k + 3) * 128 + f0];
#pragma unroll
        for (int i = 0; i < 8; i++) {
            float4 a = *(const float4*)&As[wv][i][k];
            acc[i].x += a.x * w0.x + a.y * w1.x + a.z * w2.x + a.w * w3.x;
            acc[i].y += a.x * w0.y + a.y * w1.y + a.z * w2.y + a.w * w3.y;
        }
    }
    {   // rows 76,77
        float2 w0 = *(const float2*)&W[76 * 128 + f0];
        float2 w1 = *(const float2*)&W[77 * 128 + f0];
#pragma unroll
        for (int i = 0; i < 8; i++) {
            float2 a = *(const float2*)&As[wv][i][76];
            acc[i].x += a.x * w0.x + a.y * w1.x;
            acc[i].y += a.x * w0.y + a.y * w1.y;
        }
    }
    float2 bv = *(const float2*)&bias[f0];
#pragma unroll
    for (int i = 0; i < 8; i++) {
        float ox = fmaxf(acc[i].x + bv.x, 0.f);
        float oy = fmaxf(acc[i].y + bv.y, 0.f);
        *(__half2*)&out[(size_t)(n0 + i) * 128 + f0] = __floats2half2_rn(ox, oy);
    }
}

// ---------------- fused2: pair-zip fp16 gather128 + gemm2(pk_fma) + pool ----------------
// 4 waves/block, wave owns 8 nodes (4 pairs); all 64 lanes gather (__half2 =
// 4B/lane, 256B rows). GEMM: lane covers 4 of 256 out-feats, packed-f32 fma;
// pool: flush-on-change segment-max (batch sorted) with atomicMax.
__global__ __launch_bounds__(256) void k_fused2(const __half* __restrict__ h,
    const int* __restrict__ rp, const int2* __restrict__ es,
    const float* __restrict__ dinv, const float* __restrict__ W,
    const float* __restrict__ bias, const int* __restrict__ batch,
    unsigned* __restrict__ gmax) {
    __shared__ float As[4][8][128];  // 16 KB
    int tid = threadIdx.x;
    int wv = tid >> 6, l = tid & 63;
    int task = __builtin_amdgcn_readfirstlane(blockIdx.x * 4 + wv);  // 12500 tasks
    int n0 = task * 8;
    if (n0 >= NN) return;

    for (int pi = 0; pi < 4; pi++) {
        int nA = n0 + 2 * pi, nB = nA + 1;
        float diA = dinv[nA], swA = diA * diA;
        float diB = dinv[nB], swB = diB * diB;
        float2 aA = __half22float2(((const __half2*)(h + (size_t)nA * 128))[l]);
        float2 aB = __half22float2(((const __half2*)(h + (size_t)nB * 128))[l]);
        aA.x *= swA; aA.y *= swA;
        aB.x *= swB; aB.y *= swB;
        int eA = rp[nA], eA1 = rp[nA + 1];
        int eB = rp[nB], eB1 = rp[nB + 1];
        int cA = (eA1 - eA) >> 3, cB = (eB1 - eB) >> 3;
        while (cA > 0 || cB > 0) {
            bool dA = (cA > 0), dB = (cB > 0);
            int2 esA[8], esB[8];
            __half2 vA[8], vB[8];
            if (dA) {
#pragma unroll
                for (int j = 0; j < 8; j++) esA[j] = es[eA + j];
            }
            if (dB) {
#pragma unroll
                for (int j = 0; j < 8; j++) esB[j] = es[eB + j];
            }
            if (dA) {
#pragma unroll
                for (int j = 0; j < 8; j++)
                    vA[j] = ((const __half2*)(h + (size_t)esA[j].x * 128))[l];
            }
            if (dB) {
#pragma unroll
                for (int j = 0; j < 8; j++)
                    vB[j] = ((const __half2*)(h + (size_t)esB[j].x * 128))[l];
            }
            if (dA) {
#pragma unroll
                for (int j = 0; j < 8; j++) {
                    float w = __int_as_float(esA[j].y);
                    float2 v = __half22float2(vA[j]);
                    aA.x += v.x * w; aA.y += v.y * w;
                }
                eA += 8; cA--;
            }
            if (dB) {
#pragma unroll
                for (int j = 0; j < 8; j++) {
                    float w = __int_as_float(esB[j].y);
                    float2 v = __half22float2(vB[j]);
                    aB.x += v.x * w; aB.y += v.y * w;
                }
                eB += 8; cB--;
            }
        }
        while (eA < eA1 && eB < eB1) {
            int2 pA = es[eA], pB = es[eB];
            float2 vA2 = __half22float2(((const __half2*)(h + (size_t)pA.x * 128))[l]);
            float2 vB2 = __half22float2(((const __half2*)(h + (size_t)pB.x * 128))[l]);
            float wA = __int_as_float(pA.y), wB = __int_as_float(pB.y);
            aA.x += vA2.x * wA; aA.y += vA2.y * wA;
            aB.x += vB2.x * wB; aB.y += vB2.y * wB;
            eA++; eB++;
        }
        for (; eA < eA1; eA++) {
            int2 p = es[eA];
            float w = __int_as_float(p.y);
            float2 v = __half22float2(((const __half2*)(h + (size_t)p.x * 128))[l]);
            aA.x += v.x * w; aA.y += v.y * w;
        }
        for (; eB < eB1; eB++) {
            int2 p = es[eB];
            float w = __int_as_float(p.y);
            float2 v = __half22float2(((const __half2*)(h + (size_t)p.x * 128))[l]);
            aB.x += v.x * w; aB.y += v.y * w;
        }
        *(float2*)&As[wv][2 * pi][2 * l] = aA;
        *(float2*)&As[wv][2 * pi + 1][2 * l] = aB;
    }
    // same-wave producer/consumer: no barrier needed.

    int f0 = l * 4;
    v2f acc[8][2];
#pragma unroll
    for (int i = 0; i < 8; i++) { acc[i][0] = (v2f)(0.f); acc[i][1] = (v2f)(0.f); }

    for (int k = 0; k < 128; k += 4) {
        float4 w0 = *(const float4*)&W[(size_t)(k + 0) * 256 + f0];
        float4 w1 = *(const float4*)&W[(size_t)(k + 1) * 256 + f0];
        float4 w2 = *(const float4*)&W[(size_t)(k + 2) * 256 + f0];
        float4 w3 = *(const float4*)&W[(size_t)(k + 3) * 256 + f0];
        v2f w0a = {w0.x, w0.y}, w0b = {w0.z, w0.w};
        v2f w1a = {w1.x, w1.y}, w1b = {w1.z, w1.w};
        v2f w2a = {w2.x, w2.y}, w2b = {w2.z, w2.w};
        v2f w3a = {w3.x, w3.y}, w3b = {w3.z, w3.w};
#pragma unroll
        for (int i = 0; i < 8; i++) {
            float4 a = *(const float4*)&As[wv][i][k];
            v2f sx = {a.x, a.x}, sy = {a.y, a.y}, sz = {a.z, a.z}, sw = {a.w, a.w};
            acc[i][0] = __builtin_elementwise_fma(sx, w0a, acc[i][0]);
            acc[i][1] = __builtin_elementwise_fma(sx, w0b, acc[i][1]);
            acc[i][0] = __builtin_elementwise_fma(sy, w1a, acc[i][0]);
            acc[i][1] = __builtin_elementwise_fma(sy, w1b, acc[i][1]);
            acc[i][0] = __builtin_elementwise_fma(sz, w2a, acc[i][0]);
            acc[i][1] = __builtin_elementwise_fma(sz, w2b, acc[i][1]);
            acc[i][0] = __builtin_elementwise_fma(sw, w3a, acc[i][0]);
            acc[i][1] = __builtin_elementwise_fma(sw, w3b, acc[i][1]);
        }
    }

    float4 bv = *(const float4*)&bias[f0];
    int curg = -1;
    float4 m = make_float4(0.f, 0.f, 0.f, 0.f);
#pragma unroll
    for (int i = 0; i < 8; i++) {
        int g = batch[n0 + i];
        float4 v;
        v.x = fmaxf(acc[i][0].x + bv.x, 0.f); v.y = fmaxf(acc[i][0].y + bv.y, 0.f);
        v.z = fmaxf(acc[i][1].x + bv.z, 0.f); v.w = fmaxf(acc[i][1].y + bv.w, 0.f);
        if (g != curg) {
            if (curg >= 0) {
                unsigned* gp = &gmax[(size_t)curg * 256 + f0];
                atomicMax(&gp[0], __float_as_uint(m.x));
                atomicMax(&gp[1], __float_as_uint(m.y));
                atomicMax(&gp[2], __float_as_uint(m.z));
                atomicMax(&gp[3], __float_as_uint(m.w));
            }
            curg = g; m = v;
        } else {
            m.x = fmaxf(m.x, v.x); m.y = fmaxf(m.y, v.y);
            m.z = fmaxf(m.z, v.z); m.w = fmaxf(m.w, v.w);
        }
    }
    if (curg >= 0) {
        unsigned* gp = &gmax[(size_t)curg * 256 + f0];
        atomicMax(&gp[0], __float_as_uint(m.x));
        atomicMax(&gp[1], __float_as_uint(m.y));
        atomicMax(&gp[2], __float_as_uint(m.z));
        atomicMax(&gp[3], __float_as_uint(m.w));
    }
}

// ---------------- MLP head ----------------

// 8 graphs/block: W streamed once per 8 graphs (64 blocks total)
__global__ __launch_bounds__(256) void k_gemm3(const float* __restrict__ A,
    const float* __restrict__ W, const float* __restrict__ bias,
    float* __restrict__ out) {
    __shared__ float rs[8][256];   // 8 KB
    int b = blockIdx.x, tid = threadIdx.x;    // 64 blocks
#pragma unroll
    for (int g = 0; g < 8; g++) rs[g][tid] = A[(b * 8 + g) * 256 + tid];
    __syncthreads();
    float acc[8][4];
#pragma unroll
    for (int g = 0; g < 8; g++)
#pragma unroll
        for (int j = 0; j < 4; j++) acc[g][j] = 0.f;
    for (int k = 0; k < 256; k++) {
        float w0 = W[k * 1024 + tid];
        float w1 = W[k * 1024 + tid + 256];
        float w2 = W[k * 1024 + tid + 512];
        float w3 = W[k * 1024 + tid + 768];
#pragma unroll
        for (int g = 0; g < 8; g++) {
            float a = rs[g][k];
            acc[g][0] += a * w0; acc[g][1] += a * w1;
            acc[g][2] += a * w2; acc[g][3] += a * w3;
        }
    }
#pragma unroll
    for (int g = 0; g < 8; g++)
#pragma unroll
        for (int j = 0; j < 4; j++) {
            int f = tid + j * 256;
            out[(b * 8 + g) * 1024 + f] = fmaxf(acc[g][j] + bias[f], 0.0f);
        }
}

__global__ __launch_bounds__(128) void k_gemm4(const float* __restrict__ A,
    const float* __restrict__ W, const float* __restrict__ bias,
    float* __restrict__ out) {
    __shared__ float rs[4][1024];   // 16 KB
    int b = blockIdx.x, tid = threadIdx.x;    // 128 blocks
    for (int i = tid; i < 4096; i += 128) rs[i >> 10][i & 1023] = A[b * 4096 + i];
    __syncthreads();
    float acc[4] = {0.f, 0.f, 0.f, 0.f};
    for (int k = 0; k < 1024; k++) {
        float wv = W[k * 128 + tid];
#pragma unroll
        for (int g = 0; g < 4; g++) acc[g] += rs[g][k] * wv;
    }
#pragma unroll
    for (int g = 0; g < 4; g++)
        out[(b * 4 + g) * 128 + tid] = acc[g] + bias[tid];
}

extern "C" void kernel_launch(void* const* d_in, const int* in_sizes, int n_in,
                              void* d_out, int out_size, void* d_ws, size_t ws_size,
                              hipStream_t stream) {
    const float* x    = (const float*)d_in[0];
    const int*   ei   = (const int*)d_in[1];
    const int*   batch= (const int*)d_in[2];
    const float* W1   = (const float*)d_in[3];
    const float* b1   = (const float*)d_in[4];
    const float* W2   = (const float*)d_in[5];
    const float* b2   = (const float*)d_in[6];
    const float* Wg1  = (const float*)d_in[7];
    const float* bg1  = (const float*)d_in[8];
    const float* Wg2  = (const float*)d_in[9];
    const float* bg2  = (const float*)d_in[10];
    const int* src = ei;
    const int* dst = ei + NE;

    char* w8 = (char*)d_ws;
    int*   cnt     = (int*)w8;                 w8 += (size_t)NN * 4;
    int*   row_ptr = (int*)w8;                 w8 += (size_t)(NN + 4) * 4;
    int*   cursor  = (int*)w8;                 w8 += (size_t)NN * 4;
    int*   bsum    = (int*)w8;                 w8 += 128 * 4;
    int2*  es      = (int2*)w8;                w8 += (size_t)NE * 8;
    float* dinv    = (float*)w8;               w8 += (size_t)NN * 4;
    __half* xh     = (__half*)w8;              w8 += (size_t)NN * 78 * 2;
    __half* h1     = (__half*)w8;              w8 += (size_t)NN * 128 * 2;
    unsigned* gmax = (unsigned*)w8;            w8 += (size_t)NG * 256 * 4;
    float* g1      = (float*)w8;               w8 += (size_t)NG * 1024 * 4;

    // CSR build + x conversion
    hipMemsetAsync(cnt, 0, (size_t)NN * 4, stream);
    k_hist<<<(NE + 255) / 256, 256, 0, stream>>>(dst, cnt, NE);
    k_cvt_x<<<(NN * 39 + 255) / 256, 256, 0, stream>>>(x, xh);
    k_prep<<<(NG * 256 + 255) / 256, 256, 0, stream>>>(cnt, dinv, (float*)gmax);
    k_bsum<<<NBLK, 256, 0, stream>>>(cnt, bsum);
    k_scan_bsum<<<1, 128, 0, stream>>>(bsum, row_ptr);
    k_scan_blocks<<<NBLK, 256, 0, stream>>>(cnt, bsum, row_ptr, cursor);
    k_fillslots<<<(NE + 255) / 256, 256, 0, stream>>>(src, dst, dinv, cursor, es, NE);

    // layer 1 (fused pair-zip fp16 gather + gemm + relu -> fp16 h1)
    k_fused1<<<NN / 32, 256, 0, stream>>>(xh, row_ptr, es, dinv, W1, b1, h1);

    // layer 2 (fused pair-zip fp16 gather + gemm + relu + pool)
    k_fused2<<<NN / 32, 256, 0, stream>>>(h1, row_ptr, es, dinv, W2, b2, batch, gmax);

    // MLP head
    k_gemm3<<<NG / 8, 256, 0, stream>>>((const float*)gmax, Wg1, bg1, g1);
    k_gemm4<<<NG / 4, 128, 0, stream>>>(g1, Wg2, bg2, (float*)d_out);
}